// Round 7
// baseline (1502.909 us; speedup 1.0000x reference)
//
#include <hip/hip_runtime.h>
#include <hip/hip_bf16.h>
#include <math.h>

#define NN 100000
#define NE 1600000
#define FF 64
#define NB 64
#define NSCAN_BLOCKS 391   // ceil(NN/256)

// avg_deg['log'] = sum(log(i+1)*DEG[i]) / sum(DEG)
__device__ __constant__ float AVG_LOG_F = 1.9595436f;

typedef short short8 __attribute__((ext_vector_type(8)));
typedef float f32x4 __attribute__((ext_vector_type(4)));
typedef _Float16 half2v __attribute__((ext_vector_type(2)));

__device__ __forceinline__ void atomAddF(float* p, float v) {
    __hip_atomic_fetch_add(p, v, __ATOMIC_RELAXED, __HIP_MEMORY_SCOPE_AGENT);
}
__device__ __forceinline__ float bf2f(short v) {
    return __uint_as_float(((unsigned)(unsigned short)v) << 16);
}
__device__ __forceinline__ half2v i2h2(int v) {
    return __builtin_bit_cast(half2v, v);
}

// ---------------- fold weights: Wtb = (Wo@Wl)^T in bf16, We'=We@Wp2, biases ----------------
__global__ void fold_weights(const float* __restrict__ Wo, const float* __restrict__ Wl,
                             const float* __restrict__ bo, const float* __restrict__ bl,
                             const float* __restrict__ We, const float* __restrict__ Wp,
                             const float* __restrict__ bp, const float* __restrict__ be,
                             __hip_bfloat16* __restrict__ Wtb,   // [64][832]  Wtb[f][k] = (Wo@Wl)[k][f]
                             float* __restrict__ Wep,  // [16][64]
                             float* __restrict__ bpF, float* __restrict__ boF) {
    int t = blockIdx.x * blockDim.x + threadIdx.x;
    if (t < 832 * 64) {
        int k = t >> 6, f = t & 63;
        float acc = 0.f;
        for (int j = 0; j < 64; j++) acc += Wo[k * 64 + j] * Wl[j * 64 + f];
        Wtb[f * 832 + k] = __float2bfloat16(acc);
    } else if (t < 832 * 64 + 16 * 64) {
        int u = t - 832 * 64; int k = u >> 6, f = u & 63;
        float acc = 0.f;
        for (int j = 0; j < 64; j++) acc += We[k * 64 + j] * Wp[(128 + j) * 64 + f];
        Wep[k * 64 + f] = acc;
    } else if (t < 832 * 64 + 1024 + 64) {
        int f = t - (832 * 64 + 1024);
        float acc = bl[f];
        for (int j = 0; j < 64; j++) acc += bo[j] * Wl[j * 64 + f];
        boF[f] = acc;
    } else if (t < 832 * 64 + 1024 + 128) {
        int f = t - (832 * 64 + 1024 + 64);
        float acc = bp[f];
        for (int j = 0; j < 64; j++) acc += be[j] * Wp[(128 + j) * 64 + f];
        bpF[f] = acc;
    }
}

// ---------------- node pre-MLP + A/B projections (wave per node); Bn stored bf16 ----------------
__global__ __launch_bounds__(256) void node_pre(const float* __restrict__ x,
                                                const float* __restrict__ W1, const float* __restrict__ b1,
                                                const float* __restrict__ W2, const float* __restrict__ b2,
                                                const float* __restrict__ Wp,
                                                float* __restrict__ x2, float* __restrict__ A,
                                                __hip_bfloat16* __restrict__ Bnb) {
    __shared__ float W1s[64 * 32], W2s[32 * 64], Wp0s[64 * 64], Wp1s[64 * 64];
    __shared__ float xs[4][64], ts[4][32], x2s[4][64];
    int tid = threadIdx.x;
    for (int i = tid; i < 2048; i += 256) W1s[i] = W1[i];
    for (int i = tid; i < 2048; i += 256) W2s[i] = W2[i];
    for (int i = tid; i < 4096; i += 256) Wp0s[i] = Wp[i];
    for (int i = tid; i < 4096; i += 256) Wp1s[i] = Wp[4096 + i];
    __syncthreads();
    int w = tid >> 6, f = tid & 63;
    int wid = blockIdx.x * 4 + w;
    int nw = gridDim.x * 4;
    for (int v = wid; v < NN; v += nw) {
        xs[w][f] = x[(size_t)v * 64 + f];
        if (f < 32) {
            float tj = b1[f];
            for (int k = 0; k < 64; k++) tj += xs[w][k] * W1s[k * 32 + f];
            ts[w][f] = fmaxf(tj, 0.f);
        }
        float acc2 = b2[f];
        for (int k = 0; k < 32; k++) acc2 += ts[w][k] * W2s[k * 64 + f];
        x2s[w][f] = acc2;
        x2[(size_t)v * 64 + f] = acc2;
        float aa = 0.f, bb = 0.f;
        for (int k = 0; k < 64; k++) {
            float xv = x2s[w][k];
            aa += xv * Wp0s[k * 64 + f];
            bb += xv * Wp1s[k * 64 + f];
        }
        A[(size_t)v * 64 + f] = aa;
        Bnb[(size_t)v * 64 + f] = __float2bfloat16(bb);
    }
}

// ---------------- counting sort of edges by dst ----------------
__global__ void hist_kernel(const int* __restrict__ ei, unsigned* __restrict__ cnt_i) {
    int t = blockIdx.x * blockDim.x + threadIdx.x;
    if (t < NE) atomicAdd(&cnt_i[ei[NE + t]], 1u);
}

__global__ void scan_blocksum(const unsigned* __restrict__ cnt_i, unsigned* __restrict__ bsum) {
    __shared__ unsigned red[256];
    int t = blockIdx.x * 256 + threadIdx.x;
    unsigned c = (t < NN) ? cnt_i[t] : 0u;
    red[threadIdx.x] = c; __syncthreads();
    for (int s = 128; s > 0; s >>= 1) {
        if (threadIdx.x < s) red[threadIdx.x] += red[threadIdx.x + s];
        __syncthreads();
    }
    if (threadIdx.x == 0) bsum[blockIdx.x] = red[0];
}

__global__ void scan_top(const unsigned* __restrict__ bsum, unsigned* __restrict__ boff,
                         unsigned* __restrict__ start) {
    __shared__ unsigned sh[512];
    int t = threadIdx.x;
    unsigned v = (t < NSCAN_BLOCKS) ? bsum[t] : 0u;
    sh[t] = v; __syncthreads();
    for (int d = 1; d < 512; d <<= 1) {
        unsigned add = (t >= d) ? sh[t - d] : 0u;
        __syncthreads();
        sh[t] += add;
        __syncthreads();
    }
    if (t < NSCAN_BLOCKS) boff[t] = sh[t] - v;   // exclusive
    if (t == 0) start[NN] = NE;
}

__global__ void scan_final(const unsigned* __restrict__ cnt_i, const unsigned* __restrict__ boff,
                           unsigned* __restrict__ start) {
    __shared__ unsigned sh[256];
    int b = blockIdx.x, t = threadIdx.x;
    int v = b * 256 + t;
    unsigned c = (v < NN) ? cnt_i[v] : 0u;
    sh[t] = c; __syncthreads();
    for (int d = 1; d < 256; d <<= 1) {
        unsigned add = (t >= d) ? sh[t - d] : 0u;
        __syncthreads();
        sh[t] += add;
        __syncthreads();
    }
    if (v < NN) start[v] = boff[b] + sh[t] - c;  // exclusive scan
}

// ---------------- degree binning: sort node ids by in-degree (64 bins) ----------------
__global__ void deg_hist(const unsigned* __restrict__ cnt_i, unsigned* __restrict__ dhist) {
    int t = blockIdx.x * blockDim.x + threadIdx.x;
    if (t < NN) {
        unsigned d = cnt_i[t]; if (d > 63u) d = 63u;
        atomicAdd(&dhist[d], 1u);
    }
}
__global__ void deg_scan(const unsigned* __restrict__ dhist, unsigned* __restrict__ dcur) {
    __shared__ unsigned sh[64];
    int t = threadIdx.x;
    unsigned v = dhist[t];
    sh[t] = v; __syncthreads();
    for (int d = 1; d < 64; d <<= 1) {
        unsigned add = (t >= d) ? sh[t - d] : 0u;
        __syncthreads();
        sh[t] += add;
        __syncthreads();
    }
    dcur[t] = sh[t] - v;   // exclusive
}
__global__ void deg_scatter(const unsigned* __restrict__ cnt_i, unsigned* __restrict__ dcur,
                            unsigned* __restrict__ nodeperm) {
    int t = blockIdx.x * blockDim.x + threadIdx.x;
    if (t < NN) {
        unsigned d = cnt_i[t]; if (d > 63u) d = 63u;
        unsigned p = atomicAdd(&dcur[d], 1u);
        nodeperm[p] = (unsigned)t;
    }
}

// scatter: materialize sorted edge payloads (src and f16 edge_attr); pads element NE
__global__ void scatter_kernel(const int* __restrict__ ei, const float* __restrict__ ea,
                               const unsigned* __restrict__ start,
                               unsigned* __restrict__ cnt_i,
                               unsigned short* __restrict__ eah, int* __restrict__ src_s) {
    int t = blockIdx.x * blockDim.x + threadIdx.x;
    if (t == 0) {
        src_s[NE] = 0;
        short8 z = {0, 0, 0, 0, 0, 0, 0, 0};
        short8* p = (short8*)(eah + (size_t)NE * 16);
        p[0] = z; p[1] = z;
    }
    if (t < NE) {
        int d = ei[NE + t];
        unsigned old = atomicSub(&cnt_i[d], 1u);
        unsigned pos = start[d] + old - 1u;
        src_s[pos] = ei[t];
        const float4* s4 = (const float4*)(ea + (size_t)t * 16);
        float4 a = s4[0], b = s4[1], c = s4[2], e = s4[3];
        short8 o0, o1;
        o0[0] = __builtin_bit_cast(short, (_Float16)a.x);
        o0[1] = __builtin_bit_cast(short, (_Float16)a.y);
        o0[2] = __builtin_bit_cast(short, (_Float16)a.z);
        o0[3] = __builtin_bit_cast(short, (_Float16)a.w);
        o0[4] = __builtin_bit_cast(short, (_Float16)b.x);
        o0[5] = __builtin_bit_cast(short, (_Float16)b.y);
        o0[6] = __builtin_bit_cast(short, (_Float16)b.z);
        o0[7] = __builtin_bit_cast(short, (_Float16)b.w);
        o1[0] = __builtin_bit_cast(short, (_Float16)c.x);
        o1[1] = __builtin_bit_cast(short, (_Float16)c.y);
        o1[2] = __builtin_bit_cast(short, (_Float16)c.z);
        o1[3] = __builtin_bit_cast(short, (_Float16)c.w);
        o1[4] = __builtin_bit_cast(short, (_Float16)e.x);
        o1[5] = __builtin_bit_cast(short, (_Float16)e.y);
        o1[6] = __builtin_bit_cast(short, (_Float16)e.z);
        o1[7] = __builtin_bit_cast(short, (_Float16)e.w);
        short8* dst8 = (short8*)(eah + (size_t)pos * 16);
        dst8[0] = o0; dst8[1] = o1;
    }
}

// ---------------- fused aggregation + post GEMM (MFMA) + BN stats ----------------
// block = 256 threads = 4 waves = 16 degree-sorted nodes (via nodeperm).
// Wave w interleaves its 4 node-segments in one j-loop (4x gather MLP);
// per-edge dot uses 8x v_dot2_f32_f16. Then bf16 LDS A-tile + MFMA vs Wtb.
__global__ __launch_bounds__(256) void agg_post_kernel(const unsigned short* __restrict__ eah,
                                                       const int* __restrict__ src_s,
                                                       const unsigned* __restrict__ start,
                                                       const unsigned* __restrict__ nodeperm,
                                                       const float* __restrict__ A,
                                                       const unsigned short* __restrict__ Bnb,
                                                       const float* __restrict__ x2,
                                                       const float* __restrict__ Wep, const float* __restrict__ bpF,
                                                       const __hip_bfloat16* __restrict__ Wtb,
                                                       const float* __restrict__ boF,
                                                       float* __restrict__ out_pre,
                                                       float* __restrict__ bnsum, float* __restrict__ bnsum2) {
    __shared__ __hip_bfloat16 As[16 * 840];
    __shared__ int nids[16];
    int tid = threadIdx.x, w = tid >> 6, f = tid & 63;
    int base = blockIdx.x * 16;      // 6250 blocks exactly

    if (tid < 16) nids[tid] = (int)nodeperm[base + tid];

    half2v wp[8];
    #pragma unroll
    for (int k = 0; k < 8; k++) {
        wp[k][0] = (_Float16)Wep[(2 * k) * 64 + f];
        wp[k][1] = (_Float16)Wep[(2 * k + 1) * 64 + f];
    }
    float bpf = bpF[f];
    __syncthreads();

    unsigned s0[4]; int len[4], lim[4]; float av[4];
    float sA[4] = {0.f, 0.f, 0.f, 0.f}, s2A[4] = {0.f, 0.f, 0.f, 0.f};
    float mnA[4], mxA[4];
    int vg[4];
    int maxlen = 0;
    #pragma unroll
    for (int g = 0; g < 4; ++g) {
        int v = nids[g * 4 + w];
        vg[g] = v;
        unsigned a = start[v], b = start[v + 1];
        s0[g] = a; len[g] = (int)(b - a);
        lim[g] = len[g] > 0 ? len[g] - 1 : 0;
        maxlen = max(maxlen, len[g]);
        av[g] = A[(size_t)v * 64 + f] + bpf;
        mnA[g] = INFINITY; mxA[g] = -INFINITY;
    }

    for (int j = 0; j < maxlen; ++j) {
        int src[4]; int4 E0[4], E1[4];
        #pragma unroll
        for (int g = 0; g < 4; ++g) {
            unsigned idx = s0[g] + (unsigned)min(j, lim[g]);
            src[g] = src_s[idx];
            const int4* ep = (const int4*)(eah + (size_t)idx * 16);
            E0[g] = ep[0]; E1[g] = ep[1];
        }
        float bn[4];
        #pragma unroll
        for (int g = 0; g < 4; ++g)
            bn[g] = bf2f((short)Bnb[(size_t)src[g] * 64 + f]);
        #pragma unroll
        for (int g = 0; g < 4; ++g) {
            float h = av[g] + bn[g];
            h = __builtin_amdgcn_fdot2(i2h2(E0[g].x), wp[0], h, false);
            h = __builtin_amdgcn_fdot2(i2h2(E0[g].y), wp[1], h, false);
            h = __builtin_amdgcn_fdot2(i2h2(E0[g].z), wp[2], h, false);
            h = __builtin_amdgcn_fdot2(i2h2(E0[g].w), wp[3], h, false);
            h = __builtin_amdgcn_fdot2(i2h2(E1[g].x), wp[4], h, false);
            h = __builtin_amdgcn_fdot2(i2h2(E1[g].y), wp[5], h, false);
            h = __builtin_amdgcn_fdot2(i2h2(E1[g].z), wp[6], h, false);
            h = __builtin_amdgcn_fdot2(i2h2(E1[g].w), wp[7], h, false);
            bool valid = j < len[g];
            float hm = valid ? h : 0.f;
            sA[g] += hm; s2A[g] += hm * hm;
            mnA[g] = fminf(mnA[g], valid ? h : INFINITY);
            mxA[g] = fmaxf(mxA[g], valid ? h : -INFINITY);
        }
    }

    #pragma unroll
    for (int g = 0; g < 4; ++g) {
        int n = g * 4 + w;
        int v = vg[g];
        float c = (float)len[g];
        float d = fmaxf(c, 1.f);
        float inv = 1.f / d;
        float mean = sA[g] * inv, mean2 = s2A[g] * inv;
        float sd = sqrtf(fmaxf(mean2 - mean * mean, 0.f) + 1e-5f);
        bool has = len[g] > 0;
        float mn = has ? mnA[g] : 0.f;
        float mx = has ? mxA[g] : 0.f;
        float l = __logf(d + 1.f);
        float amp = l * (1.0f / 1.9595436f);
        float iamp = 1.9595436f / l;
        __hip_bfloat16* row = &As[n * 840];
        row[f]        = __float2bfloat16(x2[(size_t)v * 64 + f]);
        row[64 + f]   = __float2bfloat16(mean);
        row[128 + f]  = __float2bfloat16(mn);
        row[192 + f]  = __float2bfloat16(mx);
        row[256 + f]  = __float2bfloat16(sd);
        row[320 + f]  = __float2bfloat16(mean * amp);
        row[384 + f]  = __float2bfloat16(mn * amp);
        row[448 + f]  = __float2bfloat16(mx * amp);
        row[512 + f]  = __float2bfloat16(sd * amp);
        row[576 + f]  = __float2bfloat16(mean * iamp);
        row[640 + f]  = __float2bfloat16(mn * iamp);
        row[704 + f]  = __float2bfloat16(mx * iamp);
        row[768 + f]  = __float2bfloat16(sd * iamp);
    }
    __syncthreads();

    // MFMA phase: lane = m + 16q; A[m][k=q*8+j], B[k][n=m]; D: col=lane&15, row=q*4+reg
    int m = f & 15, q = f >> 4;
    int fbase = w * 16;
    f32x4 acc = {0.f, 0.f, 0.f, 0.f};
    const __hip_bfloat16* arow = &As[m * 840 + q * 8];
    const __hip_bfloat16* brow = &Wtb[(size_t)(fbase + m) * 832 + q * 8];
    #pragma unroll
    for (int s = 0; s < 26; ++s) {
        short8 af = *(const short8*)(arow + s * 32);
        short8 bf = *(const short8*)(brow + s * 32);
        acc = __builtin_amdgcn_mfma_f32_16x16x32_bf16(af, bf, acc, 0, 0, 0);
    }

    float bof = boF[fbase + m];
    float p1 = 0.f, p2 = 0.f;
    #pragma unroll
    for (int r = 0; r < 4; ++r) {
        float vv = acc[r] + bof;
        out_pre[(size_t)nids[q * 4 + r] * 64 + fbase + m] = vv;
        p1 += vv; p2 += vv * vv;
    }
    p1 += __shfl_xor(p1, 16); p2 += __shfl_xor(p2, 16);
    p1 += __shfl_xor(p1, 32); p2 += __shfl_xor(p2, 32);
    if (f < 16) {
        atomAddF(&bnsum[fbase + f], p1);
        atomAddF(&bnsum2[fbase + f], p2);
    }
}

// ---------------- BN finalize ----------------
__global__ void bn_finalize(const float* __restrict__ bnsum, const float* __restrict__ bnsum2,
                            const float* __restrict__ gamma, const float* __restrict__ beta,
                            float* __restrict__ bnscale, float* __restrict__ bnshift) {
    int f = threadIdx.x;
    if (f < 64) {
        float mu = bnsum[f] * (1.0f / NN);
        float var = bnsum2[f] * (1.0f / NN) - mu * mu;
        float sc = gamma[f] / sqrtf(var + 1e-5f);
        bnscale[f] = sc;
        bnshift[f] = beta[f] - mu * sc;
    }
}

// ---------------- BN apply + ReLU + global_add_pool ----------------
__global__ __launch_bounds__(256) void bn_pool(const float* __restrict__ out_pre, const int* __restrict__ batch,
                                               const float* __restrict__ bnscale, const float* __restrict__ bnshift,
                                               float* __restrict__ pooled) {
    __shared__ float red[256];
    int tid = threadIdx.x, f = tid & 63, q = tid >> 6;
    int base = blockIdx.x * 64;
    float sc = bnscale[f], sh = bnshift[f];
    int b_first = batch[base < NN ? base : NN - 1];
    int last = base + 63; if (last >= NN) last = NN - 1;
    int b_last = batch[last];
    if (b_first == b_last) {
        float local = 0.f;
        for (int g = 0; g < 16; ++g) {
            int v = base + g * 4 + q;
            if (v < NN) local += fmaxf(out_pre[(size_t)v * 64 + f] * sc + sh, 0.f);
        }
        red[tid] = local;
        __syncthreads();
        if (tid < 64) atomAddF(&pooled[b_first * 64 + f], red[f] + red[f + 64] + red[f + 128] + red[f + 192]);
    } else {
        for (int g = 0; g < 16; ++g) {
            int v = base + g * 4 + q;
            if (v < NN) {
                float val = fmaxf(out_pre[(size_t)v * 64 + f] * sc + sh, 0.f);
                atomAddF(&pooled[batch[v] * 64 + f], val);
            }
        }
    }
}

// ---------------- head MLP: relu(pooled@Wm1+bm1)@Wm2+bm2 ----------------
__global__ void head_kernel(const float* __restrict__ pooled,
                            const float* __restrict__ Wm1, const float* __restrict__ bm1,
                            const float* __restrict__ Wm2, const float* __restrict__ bm2,
                            float* __restrict__ out) {
    __shared__ float ts[64][104];
    int tid = threadIdx.x;
    for (int t = tid; t < 64 * 100; t += 256) {
        int b = t / 100, j = t % 100;
        float acc = bm1[j];
        for (int k = 0; k < 64; k++) acc += pooled[b * 64 + k] * Wm1[k * 100 + j];
        ts[b][j] = fmaxf(acc, 0.f);
    }
    __syncthreads();
    if (tid < 64) {
        float acc = bm2[0];
        for (int j = 0; j < 100; j++) acc += ts[tid][j] * Wm2[j];
        out[tid] = acc;
    }
}

extern "C" void kernel_launch(void* const* d_in, const int* in_sizes, int n_in,
                              void* d_out, int out_size, void* d_ws, size_t ws_size,
                              hipStream_t stream) {
    const float* x    = (const float*)d_in[0];
    const float* ea   = (const float*)d_in[1];
    const int*   ei   = (const int*)d_in[2];
    const int*   batch= (const int*)d_in[3];
    const float* W1   = (const float*)d_in[4];
    const float* b1   = (const float*)d_in[5];
    const float* W2   = (const float*)d_in[6];
    const float* b2   = (const float*)d_in[7];
    const float* We   = (const float*)d_in[8];
    const float* be   = (const float*)d_in[9];
    const float* Wp   = (const float*)d_in[10];
    const float* bp   = (const float*)d_in[11];
    const float* Wo   = (const float*)d_in[12];
    const float* bo   = (const float*)d_in[13];
    const float* Wl   = (const float*)d_in[14];
    const float* bl   = (const float*)d_in[15];
    const float* gamma= (const float*)d_in[16];
    const float* beta = (const float*)d_in[17];
    const float* Wm1  = (const float*)d_in[18];
    const float* bm1  = (const float*)d_in[19];
    const float* Wm2  = (const float*)d_in[20];
    const float* bm2  = (const float*)d_in[21];

    float* ws = (float*)d_ws;
    constexpr size_t NF = (size_t)NN * 64;              // 6,400,000
    const size_t o_x2     = 0;
    const size_t o_B      = NF;                         // Bnb bf16
    const size_t o_A      = 2 * NF;
    const size_t o_outpre = 3 * NF;
    const size_t o_start  = 4 * NF;                     // NN+1 uints
    const size_t o_cnt_i  = o_start + NN + 2;           // NN uints (memset 0)
    const size_t o_bsum   = o_cnt_i + NN;
    const size_t o_boff   = o_bsum + 512;
    const size_t o_nperm  = o_boff + 512;               // NN uints
    const size_t o_eah    = o_nperm + NN;               // (NE+1)*16 f16 = (NE+1)*8 float slots
    const size_t o_srcs   = o_eah + (size_t)(NE + 1) * 8;  // NE+1 ints
    const size_t o_Wtb    = o_srcs + NE + 2;
    const size_t o_Wep    = o_Wtb + 64 * 832 / 2;
    const size_t o_bpF    = o_Wep + 16 * 64;
    const size_t o_boF    = o_bpF + 64;
    const size_t o_bnscale= o_boF + 64;
    const size_t o_bnshift= o_bnscale + 64;
    const size_t o_pooled = o_bnshift + 64;             // zero block start
    const size_t o_bnsum  = o_pooled + 64 * 64;
    const size_t o_bnsum2 = o_bnsum + 64;
    const size_t o_dhist  = o_bnsum2 + 64;              // 64 uints (zeroed)
    const size_t o_dcur   = o_dhist + 64;               // 64 uints (written by deg_scan)

    hipMemsetAsync(ws + o_cnt_i, 0, NN * sizeof(unsigned), stream);
    hipMemsetAsync(ws + o_pooled, 0, (64 * 64 + 128 + 64) * sizeof(float), stream);

    fold_weights<<<213, 256, 0, stream>>>(Wo, Wl, bo, bl, We, Wp, bp, be,
                                          (__hip_bfloat16*)(ws + o_Wtb), ws + o_Wep, ws + o_bpF, ws + o_boF);
    node_pre<<<1024, 256, 0, stream>>>(x, W1, b1, W2, b2, Wp,
                                       ws + o_x2, ws + o_A, (__hip_bfloat16*)(ws + o_B));
    hist_kernel<<<6250, 256, 0, stream>>>(ei, (unsigned*)(ws + o_cnt_i));
    // degree binning (uses cnt_i degrees, before scatter destroys them)
    deg_hist<<<NSCAN_BLOCKS, 256, 0, stream>>>((const unsigned*)(ws + o_cnt_i), (unsigned*)(ws + o_dhist));
    deg_scan<<<1, 64, 0, stream>>>((const unsigned*)(ws + o_dhist), (unsigned*)(ws + o_dcur));
    deg_scatter<<<NSCAN_BLOCKS, 256, 0, stream>>>((const unsigned*)(ws + o_cnt_i), (unsigned*)(ws + o_dcur),
                                                  (unsigned*)(ws + o_nperm));
    scan_blocksum<<<NSCAN_BLOCKS, 256, 0, stream>>>((unsigned*)(ws + o_cnt_i), (unsigned*)(ws + o_bsum));
    scan_top<<<1, 512, 0, stream>>>((unsigned*)(ws + o_bsum), (unsigned*)(ws + o_boff),
                                    (unsigned*)(ws + o_start));
    scan_final<<<NSCAN_BLOCKS, 256, 0, stream>>>((unsigned*)(ws + o_cnt_i), (unsigned*)(ws + o_boff),
                                                 (unsigned*)(ws + o_start));
    scatter_kernel<<<6250, 256, 0, stream>>>(ei, ea, (const unsigned*)(ws + o_start),
                                             (unsigned*)(ws + o_cnt_i),
                                             (unsigned short*)(ws + o_eah), (int*)(ws + o_srcs));
    agg_post_kernel<<<6250, 256, 0, stream>>>((const unsigned short*)(ws + o_eah),
                                              (const int*)(ws + o_srcs),
                                              (const unsigned*)(ws + o_start),
                                              (const unsigned*)(ws + o_nperm),
                                              ws + o_A, (const unsigned short*)(ws + o_B), ws + o_x2,
                                              ws + o_Wep, ws + o_bpF,
                                              (const __hip_bfloat16*)(ws + o_Wtb), ws + o_boF,
                                              ws + o_outpre, ws + o_bnsum, ws + o_bnsum2);
    bn_finalize<<<1, 64, 0, stream>>>(ws + o_bnsum, ws + o_bnsum2, gamma, beta,
                                      ws + o_bnscale, ws + o_bnshift);
    bn_pool<<<1563, 256, 0, stream>>>(ws + o_outpre, batch,
                                      ws + o_bnscale, ws + o_bnshift, ws + o_pooled);
    head_kernel<<<1, 256, 0, stream>>>(ws + o_pooled, Wm1, bm1, Wm2, bm2, (float*)d_out);
}